// Round 5
// baseline (573.581 us; speedup 1.0000x reference)
//
#include <hip/hip_runtime.h>

#define HD 128
#define RNUM 8
#define SCAN_BS 2048

typedef __attribute__((ext_vector_type(8))) short short8;
typedef __attribute__((ext_vector_type(4))) float float4e;

__device__ __forceinline__ unsigned short f2bf(float f) {
    unsigned int u = __float_as_uint(f);
    u += 0x7fffu + ((u >> 16) & 1u);   // RNE
    return (unsigned short)(u >> 16);
}

// accumulate 2 bf16 packed in u into a[i], a[i+1]
__device__ __forceinline__ void acc2(float4e& a, unsigned int u, int i) {
    a[i]     += __uint_as_float(u << 16);
    a[i + 1] += __uint_as_float(u & 0xffff0000u);
}

// ---------------- small kernels ----------------
__global__ void zero_i(int* __restrict__ p, int n) {
    int g = blockIdx.x * blockDim.x + threadIdx.x;
    if (g < n) p[g] = 0;
}

// f32 -> bf16 bulk convert (8 elems/thread)
__global__ void tobf16_kernel(const float* __restrict__ in, unsigned short* __restrict__ out,
                              long long n8) {
    long long g = (long long)blockIdx.x * blockDim.x + threadIdx.x;
    if (g >= n8) return;
    const float4* p = (const float4*)(in + g * 8);
    float4 v0 = p[0], v1 = p[1];
    uint4 o;
    o.x = (unsigned int)f2bf(v0.x) | ((unsigned int)f2bf(v0.y) << 16);
    o.y = (unsigned int)f2bf(v0.z) | ((unsigned int)f2bf(v0.w) << 16);
    o.z = (unsigned int)f2bf(v1.x) | ((unsigned int)f2bf(v1.y) << 16);
    o.w = (unsigned int)f2bf(v1.z) | ((unsigned int)f2bf(v1.w) << 16);
    *(uint4*)(out + g * 8) = o;
}

// ---------------- CSR build: count -> scan -> fill ----------------
__global__ void count_kernel(const int* __restrict__ ei, const int* __restrict__ et,
                             int* __restrict__ cnt, int E, int N) {
    int e = blockIdx.x * blockDim.x + threadIdx.x;
    if (e < E) atomicAdd(&cnt[et[e] * N + ei[E + e]], 1);
}

__global__ void scan1(const int* __restrict__ in, int* __restrict__ out,
                      int* __restrict__ bsum, int n) {
    __shared__ int s[256];
    const int tid = threadIdx.x;
    const int base = blockIdx.x * SCAN_BS + tid * 8;
    int v[8];
    int sum = 0;
#pragma unroll
    for (int j = 0; j < 8; j++) {
        int x = (base + j < n) ? in[base + j] : 0;
        v[j] = sum;
        sum += x;
    }
    s[tid] = sum;
    __syncthreads();
    for (int off = 1; off < 256; off <<= 1) {
        int tv = (tid >= off) ? s[tid - off] : 0;
        __syncthreads();
        if (tid >= off) s[tid] += tv;
        __syncthreads();
    }
    int excl = (tid > 0) ? s[tid - 1] : 0;
    if (tid == 255) bsum[blockIdx.x] = s[255];
#pragma unroll
    for (int j = 0; j < 8; j++)
        if (base + j < n) out[base + j] = v[j] + excl;
}

__global__ void scan2(int* __restrict__ bsum, int nb) {
    __shared__ int s[512];
    const int tid = threadIdx.x;
    s[tid] = (tid < nb) ? bsum[tid] : 0;
    __syncthreads();
    for (int off = 1; off < 512; off <<= 1) {
        int tv = (tid >= off) ? s[tid - off] : 0;
        __syncthreads();
        if (tid >= off) s[tid] += tv;
        __syncthreads();
    }
    if (tid < nb) bsum[tid] = (tid > 0) ? s[tid - 1] : 0;
}

__global__ void scan3(int* __restrict__ out, int* __restrict__ cur,
                      const int* __restrict__ bsum, int n) {
    const int base = blockIdx.x * SCAN_BS + threadIdx.x * 8;
    const int add = bsum[blockIdx.x];
#pragma unroll
    for (int j = 0; j < 8; j++) {
        int i = base + j;
        if (i < n) {
            int v = out[i] + add;
            out[i] = v;
            cur[i] = v;
        }
    }
}

// fill: col = src node id (layer 2), colE = pre-resolved entity id (layer 1)
__global__ void fill_kernel(const int* __restrict__ ei, const int* __restrict__ et,
                            const int* __restrict__ ids,
                            int* __restrict__ cur, int* __restrict__ col,
                            int* __restrict__ colE, int E, int N) {
    int e = blockIdx.x * blockDim.x + threadIdx.x;
    if (e < E) {
        int src = ei[e];
        int pos = atomicAdd(&cur[et[e] * N + ei[E + e]], 1);
        col[pos] = src;
        colE[pos] = ids[src];
    }
}

// ---------------- all 18 weight mats -> bf16 transposed: WT[mat][f][d] = bf16(W[mat][d][f]) ----
__global__ void wt_all(const float* __restrict__ W1, const float* __restrict__ r1,
                       const float* __restrict__ W2, const float* __restrict__ r2,
                       unsigned short* __restrict__ WT) {
    int g = blockIdx.x * blockDim.x + threadIdx.x;
    if (g >= 18 * 16384) return;
    int mat = g >> 14;
    int idx = g & 16383;
    int d = idx >> 7;
    int f = idx & 127;
    const float* src;
    int m;
    if (mat < 8)       { src = W1; m = mat; }
    else if (mat == 8) { src = r1; m = 0; }
    else if (mat < 17) { src = W2; m = mat - 9; }
    else               { src = r2; m = 0; }
    WT[mat * 16384 + f * 128 + d] = f2bf(src[(size_t)m * 16384 + d * 128 + f]);
}

// ---------------- fused layer: agg-into-LDS + MFMA ----------------
// 256 threads = 4 waves, 64-row tile. LDS = As only (16 KB) -> 6 blocks/CU (75% occ).
// B-fragments read directly from global WT (L1/L2-hot broadcast; algebraically
// identical to the swizzled-LDS path since write/read swizzles cancel).
// x is BF16 (emb16 for layer 1, z16 for layer 2) -> 256 B/row gathers.
template <bool HAS_IDX, int ACT>   // ACT: 0 = relu -> bf16 out, 1 = sigmoid -> f32 out
__launch_bounds__(256, 6)
__global__ void rgcn_fused(const int* __restrict__ row_start, const int* __restrict__ col,
                           const int* __restrict__ ids,
                           const unsigned short* __restrict__ x16,
                           const unsigned short* __restrict__ WT,
                           const float* __restrict__ bias,
                           void* __restrict__ CoutV, int N, int E) {
    __shared__ unsigned short As[64 * 128];  // 16 KB

    const int tid = threadIdx.x;
    const int block0 = blockIdx.x * 64;
    // MFMA mapping (4 waves: 2 row strips x 2 col strips)
    const int w = tid >> 6;
    const int lane = tid & 63;
    const int ln15 = lane & 15;
    const int quad = lane >> 4;
    const int rowbase = (w & 1) * 32;
    const int colbase = (w >> 1) * 64;
    // agg mapping: 32 groups of 8 lanes; group g does rows {g, g+32}
    const int grp = tid >> 3;
    const int sub8 = tid & 7;

    float4e acc[2][4];
#pragma unroll
    for (int i = 0; i < 2; i++)
#pragma unroll
        for (int j = 0; j < 4; j++)
#pragma unroll
            for (int q = 0; q < 4; q++) acc[i][j][q] = 0.0f;

    for (int s = 0; s < 9; s++) {
        // ---- stage A tile: mean-aggregate (s<8) or root copy (s==8) ----
        if (s < RNUM) {
#pragma unroll 1
            for (int half = 0; half < 2; half++) {
                const int row = grp + half * 32;
                const int dst = block0 + row;
                float4e a0 = {0.f, 0.f, 0.f, 0.f};
                float4e a1 = {0.f, 0.f, 0.f, 0.f};
                float4e a2 = {0.f, 0.f, 0.f, 0.f};
                float4e a3 = {0.f, 0.f, 0.f, 0.f};
                float inv = 0.f;
                if (dst < N) {
                    int seg = s * N + dst;
                    int s0 = row_start[seg];
                    int s1 = (seg == RNUM * N - 1) ? E : row_start[seg + 1];
                    if (s1 > s0) inv = 1.0f / (float)(s1 - s0);
                    for (int e = s0; e < s1; e++) {
                        int c = col[e];
                        const uint4* xp = (const uint4*)(x16 + (size_t)c * HD + sub8 * 16);
                        uint4 v0 = xp[0];
                        uint4 v1 = xp[1];
                        acc2(a0, v0.x, 0); acc2(a0, v0.y, 2);
                        acc2(a1, v0.z, 0); acc2(a1, v0.w, 2);
                        acc2(a2, v1.x, 0); acc2(a2, v1.y, 2);
                        acc2(a3, v1.z, 0); acc2(a3, v1.w, 2);
                    }
                }
                a0 *= inv; a1 *= inv; a2 *= inv; a3 *= inv;
                uint4 o0, o1;
                o0.x = (unsigned int)f2bf(a0[0]) | ((unsigned int)f2bf(a0[1]) << 16);
                o0.y = (unsigned int)f2bf(a0[2]) | ((unsigned int)f2bf(a0[3]) << 16);
                o0.z = (unsigned int)f2bf(a1[0]) | ((unsigned int)f2bf(a1[1]) << 16);
                o0.w = (unsigned int)f2bf(a1[2]) | ((unsigned int)f2bf(a1[3]) << 16);
                o1.x = (unsigned int)f2bf(a2[0]) | ((unsigned int)f2bf(a2[1]) << 16);
                o1.y = (unsigned int)f2bf(a2[2]) | ((unsigned int)f2bf(a2[3]) << 16);
                o1.z = (unsigned int)f2bf(a3[0]) | ((unsigned int)f2bf(a3[1]) << 16);
                o1.w = (unsigned int)f2bf(a3[2]) | ((unsigned int)f2bf(a3[3]) << 16);
                const int ck0 = sub8 * 2;
                *(uint4*)&As[row * 128 + ((ck0 ^ (row & 15)) << 3)] = o0;
                *(uint4*)&As[row * 128 + (((ck0 + 1) ^ (row & 15)) << 3)] = o1;
            }
        } else {
            // root/self term: bf16 row copy (gather through ids for layer 1)
#pragma unroll 1
            for (int half = 0; half < 2; half++) {
                const int row = grp + half * 32;
                const int dst = block0 + row;
                uint4 o0 = {0u, 0u, 0u, 0u}, o1 = {0u, 0u, 0u, 0u};
                if (dst < N) {
                    int srcn = HAS_IDX ? ids[dst] : dst;
                    const uint4* xp = (const uint4*)(x16 + (size_t)srcn * HD + sub8 * 16);
                    o0 = xp[0];
                    o1 = xp[1];
                }
                const int ck0 = sub8 * 2;
                *(uint4*)&As[row * 128 + ((ck0 ^ (row & 15)) << 3)] = o0;
                *(uint4*)&As[row * 128 + (((ck0 + 1) ^ (row & 15)) << 3)] = o1;
            }
        }
        __syncthreads();

        // ---- MFMA: A from LDS, B straight from global WT ----
        const unsigned short* Wb = WT + s * 16384;
#pragma unroll
        for (int k0 = 0; k0 < 4; k0++) {
            short8 af[2], bf[4];
            const int ck = k0 * 4 + quad;
#pragma unroll
            for (int rt = 0; rt < 2; rt++) {
                int m = rowbase + rt * 16 + ln15;
                af[rt] = *(const short8*)&As[m * 128 + ((ck ^ (m & 15)) << 3)];
            }
#pragma unroll
            for (int ct = 0; ct < 4; ct++) {
                int n = colbase + ct * 16 + ln15;
                bf[ct] = *(const short8*)(Wb + n * 128 + ck * 8);
            }
#pragma unroll
            for (int rt = 0; rt < 2; rt++)
#pragma unroll
                for (int ct = 0; ct < 4; ct++)
                    acc[rt][ct] = __builtin_amdgcn_mfma_f32_16x16x32_bf16(
                        af[rt], bf[ct], acc[rt][ct], 0, 0, 0);
        }
        __syncthreads();
    }

    // ---- epilogue ----
#pragma unroll
    for (int ct = 0; ct < 4; ct++) {
        int ncol = colbase + ct * 16 + ln15;
        float bv = bias[ncol];
#pragma unroll
        for (int rt = 0; rt < 2; rt++) {
#pragma unroll
            for (int rg = 0; rg < 4; rg++) {
                int rowg = block0 + rowbase + rt * 16 + quad * 4 + rg;
                if (rowg < N) {
                    float v = acc[rt][ct][rg] + bv;
                    if (ACT == 0) {
                        v = fmaxf(v, 0.0f);
                        ((unsigned short*)CoutV)[(size_t)rowg * HD + ncol] = f2bf(v);
                    } else {
                        v = 1.0f / (1.0f + expf(-v));
                        ((float*)CoutV)[(size_t)rowg * HD + ncol] = v;
                    }
                }
            }
        }
    }
}

extern "C" void kernel_launch(void* const* d_in, const int* in_sizes, int n_in,
                              void* d_out, int out_size, void* d_ws, size_t ws_size,
                              hipStream_t stream) {
    const int*   x_ids = (const int*)d_in[0];
    const int*   ei    = (const int*)d_in[1];
    const int*   et    = (const int*)d_in[2];
    const float* emb   = (const float*)d_in[3];
    const float* W1    = (const float*)d_in[4];
    const float* root1 = (const float*)d_in[5];
    const float* b1    = (const float*)d_in[6];
    const float* W2    = (const float*)d_in[7];
    const float* root2 = (const float*)d_in[8];
    const float* b2    = (const float*)d_in[9];

    const int N = in_sizes[0];
    const int E = in_sizes[1] / 2;
    const int NS = RNUM * N;
    const long long embElems = (long long)in_sizes[3];   // NUM_ENTITIES * HD
    float* out = (float*)d_out;

    // ---- arenas ----
    char* ws = (char*)d_ws;
    size_t off = 0;
    int* row_start = (int*)(ws + off); off += (size_t)NS * 4;                   // 3.2 MB
    int* col       = (int*)(ws + off); off += (size_t)E * 4;                    // 2.0 MB
    int* colE      = (int*)(ws + off); off += (size_t)E * 4;                    // 2.0 MB
    int* bsum      = (int*)(ws + off); off += 4096;
    unsigned short* WT    = (unsigned short*)(ws + off); off += (size_t)18 * 16384 * 2;
    unsigned short* emb16 = (unsigned short*)(ws + off); off += (size_t)embElems * 2;  // 25.6 MB
    unsigned short* z16   = (unsigned short*)(ws + off); off += (size_t)N * HD * 2;    // 25.6 MB
    int* cur = (int*)z16;   // alias: cur dead before z16 is first written

    const int scanBlocks = (NS + SCAN_BS - 1) / SCAN_BS;
    const int layerGrid = (N + 63) / 64;

    // ---- CSR build ----
    zero_i<<<(NS + 255) / 256, 256, 0, stream>>>(cur, NS);
    count_kernel<<<(E + 255) / 256, 256, 0, stream>>>(ei, et, cur, E, N);
    scan1<<<scanBlocks, 256, 0, stream>>>(cur, row_start, bsum, NS);
    scan2<<<1, 512, 0, stream>>>(bsum, scanBlocks);
    scan3<<<scanBlocks, 256, 0, stream>>>(row_start, cur, bsum, NS);
    fill_kernel<<<(E + 255) / 256, 256, 0, stream>>>(ei, et, x_ids, cur, col, colE, E, N);

    // ---- weights -> bf16 transposed (one launch) ----
    wt_all<<<(18 * 16384 + 255) / 256, 256, 0, stream>>>(W1, root1, W2, root2, WT);

    // ---- emb -> bf16 ----
    {
        long long n8 = embElems / 8;
        tobf16_kernel<<<(unsigned int)((n8 + 255) / 256), 256, 0, stream>>>(emb, emb16, n8);
    }

    // ---- layer 1: z16 = bf16(relu(agg(emb16) + emb16[ids]@root1 + b1)) ----
    rgcn_fused<true, 0><<<layerGrid, 256, 0, stream>>>(
        row_start, colE, x_ids, emb16, WT, b1, (void*)z16, N, E);
    // ---- layer 2: out = sigmoid(agg(z16) + z16@root2 + b2) ----
    rgcn_fused<false, 1><<<layerGrid, 256, 0, stream>>>(
        row_start, col, nullptr, z16, WT + 9 * 16384, b2, (void*)out, N, E);
}

// Round 6
// 459.926 us; speedup vs baseline: 1.2471x; 1.2471x over previous
//
#include <hip/hip_runtime.h>

#define HD 128
#define RNUM 8
#define SCAN_BS 2048

typedef __attribute__((ext_vector_type(8))) short short8;
typedef __attribute__((ext_vector_type(4))) float float4e;

__device__ __forceinline__ unsigned short f2bf(float f) {
    unsigned int u = __float_as_uint(f);
    u += 0x7fffu + ((u >> 16) & 1u);   // RNE
    return (unsigned short)(u >> 16);
}

// accumulate 2 bf16 packed in u into a[i], a[i+1]
__device__ __forceinline__ void acc2(float4e& a, unsigned int u, int i) {
    a[i]     += __uint_as_float(u << 16);
    a[i + 1] += __uint_as_float(u & 0xffff0000u);
}

__device__ __forceinline__ void gload_lds16(const void* g, void* l) {
    __builtin_amdgcn_global_load_lds(
        (const __attribute__((address_space(1))) void*)g,
        (__attribute__((address_space(3))) void*)l, 16, 0, 0);
}

// ---------------- small kernels ----------------
__global__ void zero_i(int* __restrict__ p, int n) {
    int g = blockIdx.x * blockDim.x + threadIdx.x;
    if (g < n) p[g] = 0;
}

// f32 -> bf16 bulk convert (8 elems/thread)
__global__ void tobf16_kernel(const float* __restrict__ in, unsigned short* __restrict__ out,
                              long long n8) {
    long long g = (long long)blockIdx.x * blockDim.x + threadIdx.x;
    if (g >= n8) return;
    const float4* p = (const float4*)(in + g * 8);
    float4 v0 = p[0], v1 = p[1];
    uint4 o;
    o.x = (unsigned int)f2bf(v0.x) | ((unsigned int)f2bf(v0.y) << 16);
    o.y = (unsigned int)f2bf(v0.z) | ((unsigned int)f2bf(v0.w) << 16);
    o.z = (unsigned int)f2bf(v1.x) | ((unsigned int)f2bf(v1.y) << 16);
    o.w = (unsigned int)f2bf(v1.z) | ((unsigned int)f2bf(v1.w) << 16);
    *(uint4*)(out + g * 8) = o;
}

// ---------------- CSR build: count -> scan -> fill ----------------
__global__ void count_kernel(const int* __restrict__ ei, const int* __restrict__ et,
                             int* __restrict__ cnt, int E, int N) {
    int e = blockIdx.x * blockDim.x + threadIdx.x;
    if (e < E) atomicAdd(&cnt[et[e] * N + ei[E + e]], 1);
}

__global__ void scan1(const int* __restrict__ in, int* __restrict__ out,
                      int* __restrict__ bsum, int n) {
    __shared__ int s[256];
    const int tid = threadIdx.x;
    const int base = blockIdx.x * SCAN_BS + tid * 8;
    int v[8];
    int sum = 0;
#pragma unroll
    for (int j = 0; j < 8; j++) {
        int x = (base + j < n) ? in[base + j] : 0;
        v[j] = sum;
        sum += x;
    }
    s[tid] = sum;
    __syncthreads();
    for (int off = 1; off < 256; off <<= 1) {
        int tv = (tid >= off) ? s[tid - off] : 0;
        __syncthreads();
        if (tid >= off) s[tid] += tv;
        __syncthreads();
    }
    int excl = (tid > 0) ? s[tid - 1] : 0;
    if (tid == 255) bsum[blockIdx.x] = s[255];
#pragma unroll
    for (int j = 0; j < 8; j++)
        if (base + j < n) out[base + j] = v[j] + excl;
}

__global__ void scan2(int* __restrict__ bsum, int nb) {
    __shared__ int s[512];
    const int tid = threadIdx.x;
    s[tid] = (tid < nb) ? bsum[tid] : 0;
    __syncthreads();
    for (int off = 1; off < 512; off <<= 1) {
        int tv = (tid >= off) ? s[tid - off] : 0;
        __syncthreads();
        if (tid >= off) s[tid] += tv;
        __syncthreads();
    }
    if (tid < nb) bsum[tid] = (tid > 0) ? s[tid - 1] : 0;
}

__global__ void scan3(int* __restrict__ out, int* __restrict__ cur,
                      const int* __restrict__ bsum, int n) {
    const int base = blockIdx.x * SCAN_BS + threadIdx.x * 8;
    const int add = bsum[blockIdx.x];
#pragma unroll
    for (int j = 0; j < 8; j++) {
        int i = base + j;
        if (i < n) {
            int v = out[i] + add;
            out[i] = v;
            cur[i] = v;
        }
    }
}

// fill: col = src node id (layer 2), colE = pre-resolved entity id (layer 1)
__global__ void fill_kernel(const int* __restrict__ ei, const int* __restrict__ et,
                            const int* __restrict__ ids,
                            int* __restrict__ cur, int* __restrict__ col,
                            int* __restrict__ colE, int E, int N) {
    int e = blockIdx.x * blockDim.x + threadIdx.x;
    if (e < E) {
        int src = ei[e];
        int pos = atomicAdd(&cur[et[e] * N + ei[E + e]], 1);
        col[pos] = src;
        colE[pos] = ids[src];
    }
}

// ---------------- all 18 weight mats -> bf16 transposed: WT[mat][f][d] = bf16(W[mat][d][f]) ----
__global__ void wt_all(const float* __restrict__ W1, const float* __restrict__ r1,
                       const float* __restrict__ W2, const float* __restrict__ r2,
                       unsigned short* __restrict__ WT) {
    int g = blockIdx.x * blockDim.x + threadIdx.x;
    if (g >= 18 * 16384) return;
    int mat = g >> 14;
    int idx = g & 16383;
    int d = idx >> 7;
    int f = idx & 127;
    const float* src;
    int m;
    if (mat < 8)       { src = W1; m = mat; }
    else if (mat == 8) { src = r1; m = 0; }
    else if (mat < 17) { src = W2; m = mat - 9; }
    else               { src = r2; m = 0; }
    WT[mat * 16384 + f * 128 + d] = f2bf(src[(size_t)m * 16384 + d * 128 + f]);
}

// ---------------- fused layer: agg-into-LDS + MFMA, B staged in LDS via async DMA ----------
// 256 threads = 4 waves, 64-row tile. LDS = As 16 KB + Ws 32 KB = 48 KB -> 3 blocks/CU.
// Per relation s: issue Ws(s) global_load_lds DMA (latency hides under the edge walk),
// aggregate the 64x128 bf16 A-tile into LDS, barrier, MFMA from LDS, barrier.
template <bool HAS_IDX, int ACT>   // ACT: 0 = relu -> bf16 out, 1 = sigmoid -> f32 out
__launch_bounds__(256, 3)
__global__ void rgcn_fused(const int* __restrict__ row_start, const int* __restrict__ col,
                           const int* __restrict__ ids,
                           const unsigned short* __restrict__ x16,
                           const unsigned short* __restrict__ WT,
                           const float* __restrict__ bias,
                           void* __restrict__ CoutV, int N, int E) {
    __shared__ unsigned short As[64 * 128];    // 16 KB
    __shared__ unsigned short Ws[128 * 128];   // 32 KB

    const int tid = threadIdx.x;
    const int block0 = blockIdx.x * 64;
    // MFMA mapping (4 waves: 2 row strips of 32 x 2 col strips of 64)
    const int w = tid >> 6;
    const int lane = tid & 63;
    const int ln15 = lane & 15;
    const int quad = lane >> 4;
    const int rowbase = (w & 1) * 32;
    const int colbase = (w >> 1) * 64;
    // agg mapping: 32 groups of 8 lanes; group g does rows {g, g+32}
    const int grp = tid >> 3;
    const int sub8 = tid & 7;

    float4e acc[2][4];
#pragma unroll
    for (int i = 0; i < 2; i++)
#pragma unroll
        for (int j = 0; j < 4; j++)
#pragma unroll
            for (int q = 0; q < 4; q++) acc[i][j][q] = 0.0f;

    for (int s = 0; s < 9; s++) {
        // ---- stage Ws(s): async DMA (2048 x 16B chunks, 8/thread); pre-inverse-swizzled
        // global source, linear LDS dest; latency hides under the edge walk below ----
        {
            const unsigned short* Wsrc = WT + s * 16384;
#pragma unroll
            for (int i = 0; i < 8; i++) {
                int c = i * 256 + tid;
                int f = c >> 4;
                int cc = c & 15;
                const void* src = (const void*)(Wsrc + f * 128 + ((cc ^ (f & 15)) << 3));
                int cbase = i * 256 + (tid & ~63);   // wave-uniform base, +lane*16
                gload_lds16(src, (char*)Ws + (size_t)cbase * 16);
            }
        }
        // ---- stage A tile: mean-aggregate (s<8) or root copy (s==8), bf16 gathers ----
        if (s < RNUM) {
#pragma unroll 1
            for (int half = 0; half < 2; half++) {
                const int row = grp + half * 32;
                const int dst = block0 + row;
                float4e a0 = {0.f, 0.f, 0.f, 0.f};
                float4e a1 = {0.f, 0.f, 0.f, 0.f};
                float4e a2 = {0.f, 0.f, 0.f, 0.f};
                float4e a3 = {0.f, 0.f, 0.f, 0.f};
                float inv = 0.f;
                if (dst < N) {
                    int seg = s * N + dst;
                    int s0 = row_start[seg];
                    int s1 = (seg == RNUM * N - 1) ? E : row_start[seg + 1];
                    if (s1 > s0) inv = 1.0f / (float)(s1 - s0);
                    for (int e = s0; e < s1; e++) {
                        int c = col[e];
                        const uint4* xp = (const uint4*)(x16 + (size_t)c * HD + sub8 * 16);
                        uint4 v0 = xp[0];
                        uint4 v1 = xp[1];
                        acc2(a0, v0.x, 0); acc2(a0, v0.y, 2);
                        acc2(a1, v0.z, 0); acc2(a1, v0.w, 2);
                        acc2(a2, v1.x, 0); acc2(a2, v1.y, 2);
                        acc2(a3, v1.z, 0); acc2(a3, v1.w, 2);
                    }
                }
                a0 *= inv; a1 *= inv; a2 *= inv; a3 *= inv;
                uint4 o0, o1;
                o0.x = (unsigned int)f2bf(a0[0]) | ((unsigned int)f2bf(a0[1]) << 16);
                o0.y = (unsigned int)f2bf(a0[2]) | ((unsigned int)f2bf(a0[3]) << 16);
                o0.z = (unsigned int)f2bf(a1[0]) | ((unsigned int)f2bf(a1[1]) << 16);
                o0.w = (unsigned int)f2bf(a1[2]) | ((unsigned int)f2bf(a1[3]) << 16);
                o1.x = (unsigned int)f2bf(a2[0]) | ((unsigned int)f2bf(a2[1]) << 16);
                o1.y = (unsigned int)f2bf(a2[2]) | ((unsigned int)f2bf(a2[3]) << 16);
                o1.z = (unsigned int)f2bf(a3[0]) | ((unsigned int)f2bf(a3[1]) << 16);
                o1.w = (unsigned int)f2bf(a3[2]) | ((unsigned int)f2bf(a3[3]) << 16);
                const int ck0 = sub8 * 2;
                *(uint4*)&As[row * 128 + ((ck0 ^ (row & 15)) << 3)] = o0;
                *(uint4*)&As[row * 128 + (((ck0 + 1) ^ (row & 15)) << 3)] = o1;
            }
        } else {
            // root/self term: bf16 row copy (gather through ids for layer 1)
#pragma unroll 1
            for (int half = 0; half < 2; half++) {
                const int row = grp + half * 32;
                const int dst = block0 + row;
                uint4 o0 = {0u, 0u, 0u, 0u}, o1 = {0u, 0u, 0u, 0u};
                if (dst < N) {
                    int srcn = HAS_IDX ? ids[dst] : dst;
                    const uint4* xp = (const uint4*)(x16 + (size_t)srcn * HD + sub8 * 16);
                    o0 = xp[0];
                    o1 = xp[1];
                }
                const int ck0 = sub8 * 2;
                *(uint4*)&As[row * 128 + ((ck0 ^ (row & 15)) << 3)] = o0;
                *(uint4*)&As[row * 128 + (((ck0 + 1) ^ (row & 15)) << 3)] = o1;
            }
        }
        __syncthreads();

        // ---- MFMA: A and B from LDS ----
#pragma unroll
        for (int k0 = 0; k0 < 4; k0++) {
            short8 af[2], bf[4];
            const int ck = k0 * 4 + quad;
#pragma unroll
            for (int rt = 0; rt < 2; rt++) {
                int m = rowbase + rt * 16 + ln15;
                af[rt] = *(const short8*)&As[m * 128 + ((ck ^ (m & 15)) << 3)];
            }
#pragma unroll
            for (int ct = 0; ct < 4; ct++) {
                int n = colbase + ct * 16 + ln15;
                bf[ct] = *(const short8*)&Ws[n * 128 + ((ck ^ (n & 15)) << 3)];
            }
#pragma unroll
            for (int rt = 0; rt < 2; rt++)
#pragma unroll
                for (int ct = 0; ct < 4; ct++)
                    acc[rt][ct] = __builtin_amdgcn_mfma_f32_16x16x32_bf16(
                        af[rt], bf[ct], acc[rt][ct], 0, 0, 0);
        }
        __syncthreads();
    }

    // ---- epilogue ----
#pragma unroll
    for (int ct = 0; ct < 4; ct++) {
        int ncol = colbase + ct * 16 + ln15;
        float bv = bias[ncol];
#pragma unroll
        for (int rt = 0; rt < 2; rt++) {
#pragma unroll
            for (int rg = 0; rg < 4; rg++) {
                int rowg = block0 + rowbase + rt * 16 + quad * 4 + rg;
                if (rowg < N) {
                    float v = acc[rt][ct][rg] + bv;
                    if (ACT == 0) {
                        v = fmaxf(v, 0.0f);
                        ((unsigned short*)CoutV)[(size_t)rowg * HD + ncol] = f2bf(v);
                    } else {
                        v = 1.0f / (1.0f + expf(-v));
                        ((float*)CoutV)[(size_t)rowg * HD + ncol] = v;
                    }
                }
            }
        }
    }
}

extern "C" void kernel_launch(void* const* d_in, const int* in_sizes, int n_in,
                              void* d_out, int out_size, void* d_ws, size_t ws_size,
                              hipStream_t stream) {
    const int*   x_ids = (const int*)d_in[0];
    const int*   ei    = (const int*)d_in[1];
    const int*   et    = (const int*)d_in[2];
    const float* emb   = (const float*)d_in[3];
    const float* W1    = (const float*)d_in[4];
    const float* root1 = (const float*)d_in[5];
    const float* b1    = (const float*)d_in[6];
    const float* W2    = (const float*)d_in[7];
    const float* root2 = (const float*)d_in[8];
    const float* b2    = (const float*)d_in[9];

    const int N = in_sizes[0];
    const int E = in_sizes[1] / 2;
    const int NS = RNUM * N;
    const long long embElems = (long long)in_sizes[3];   // NUM_ENTITIES * HD
    float* out = (float*)d_out;

    // ---- arenas ----
    char* ws = (char*)d_ws;
    size_t off = 0;
    int* row_start = (int*)(ws + off); off += (size_t)NS * 4;                   // 3.2 MB
    int* col       = (int*)(ws + off); off += (size_t)E * 4;                    // 2.0 MB
    int* colE      = (int*)(ws + off); off += (size_t)E * 4;                    // 2.0 MB
    int* bsum      = (int*)(ws + off); off += 4096;
    unsigned short* WT    = (unsigned short*)(ws + off); off += (size_t)18 * 16384 * 2;
    unsigned short* emb16 = (unsigned short*)(ws + off); off += (size_t)embElems * 2;  // 25.6 MB
    unsigned short* z16   = (unsigned short*)(ws + off); off += (size_t)N * HD * 2;    // 25.6 MB
    int* cur = (int*)z16;   // alias: cur dead before z16 is first written

    const int scanBlocks = (NS + SCAN_BS - 1) / SCAN_BS;
    const int layerGrid = (N + 63) / 64;

    // ---- CSR build ----
    zero_i<<<(NS + 255) / 256, 256, 0, stream>>>(cur, NS);
    count_kernel<<<(E + 255) / 256, 256, 0, stream>>>(ei, et, cur, E, N);
    scan1<<<scanBlocks, 256, 0, stream>>>(cur, row_start, bsum, NS);
    scan2<<<1, 512, 0, stream>>>(bsum, scanBlocks);
    scan3<<<scanBlocks, 256, 0, stream>>>(row_start, cur, bsum, NS);
    fill_kernel<<<(E + 255) / 256, 256, 0, stream>>>(ei, et, x_ids, cur, col, colE, E, N);

    // ---- weights -> bf16 transposed (one launch) ----
    wt_all<<<(18 * 16384 + 255) / 256, 256, 0, stream>>>(W1, root1, W2, root2, WT);

    // ---- emb -> bf16 ----
    {
        long long n8 = embElems / 8;
        tobf16_kernel<<<(unsigned int)((n8 + 255) / 256), 256, 0, stream>>>(emb, emb16, n8);
    }

    // ---- layer 1: z16 = bf16(relu(agg(emb16) + emb16[ids]@root1 + b1)) ----
    rgcn_fused<true, 0><<<layerGrid, 256, 0, stream>>>(
        row_start, colE, x_ids, emb16, WT, b1, (void*)z16, N, E);
    // ---- layer 2: out = sigmoid(agg(z16) + z16@root2 + b2) ----
    rgcn_fused<false, 1><<<layerGrid, 256, 0, stream>>>(
        row_start, col, nullptr, z16, WT + 9 * 16384, b2, (void*)out, N, E);
}

// Round 8
// 407.830 us; speedup vs baseline: 1.4064x; 1.1277x over previous
//
#include <hip/hip_runtime.h>

#define HD 128
#define RNUM 8
#define SCAN_BS 2048

typedef __attribute__((ext_vector_type(8))) short short8;
typedef __attribute__((ext_vector_type(4))) float float4e;

__device__ __forceinline__ unsigned short f2bf(float f) {
    unsigned int u = __float_as_uint(f);
    u += 0x7fffu + ((u >> 16) & 1u);   // RNE
    return (unsigned short)(u >> 16);
}

__device__ __forceinline__ unsigned int pk2(float lo, float hi) {
    return (unsigned int)f2bf(lo) | ((unsigned int)f2bf(hi) << 16);
}

// accumulate 2 bf16 packed in u into a[i], a[i+1]
__device__ __forceinline__ void acc2(float4e& a, unsigned int u, int i) {
    a[i]     += __uint_as_float(u << 16);
    a[i + 1] += __uint_as_float(u & 0xffff0000u);
}

__device__ __forceinline__ void gload_lds16(const void* g, void* l) {
    __builtin_amdgcn_global_load_lds(
        (const __attribute__((address_space(1))) void*)g,
        (__attribute__((address_space(3))) void*)l, 16, 0, 0);
}

// ---------------- small kernels ----------------
__global__ void zero_i(int* __restrict__ p, int n) {
    int g = blockIdx.x * blockDim.x + threadIdx.x;
    if (g < n) p[g] = 0;
}

// weights -> bf16 transposed WT[mat][f][d], plus emb -> bf16, one launch
__global__ void prep_kernel(const float* __restrict__ W1, const float* __restrict__ r1,
                            const float* __restrict__ W2, const float* __restrict__ r2,
                            unsigned short* __restrict__ WT,
                            const float* __restrict__ emb, unsigned short* __restrict__ emb16,
                            long long n8) {
    long long g = (long long)blockIdx.x * blockDim.x + threadIdx.x;
    if (g < 18 * 16384) {
        int gi = (int)g;
        int mat = gi >> 14;
        int idx = gi & 16383;
        int d = idx >> 7;
        int f = idx & 127;
        const float* src;
        int m;
        if (mat < 8)       { src = W1; m = mat; }
        else if (mat == 8) { src = r1; m = 0; }
        else if (mat < 17) { src = W2; m = mat - 9; }
        else               { src = r2; m = 0; }
        WT[mat * 16384 + f * 128 + d] = f2bf(src[(size_t)m * 16384 + d * 128 + f]);
    }
    long long h = g - 18 * 16384;
    if (h >= 0 && h < n8) {
        const float4* p = (const float4*)(emb + h * 8);
        float4 v0 = p[0], v1 = p[1];
        uint4 o;
        o.x = pk2(v0.x, v0.y);
        o.y = pk2(v0.z, v0.w);
        o.z = pk2(v1.x, v1.y);
        o.w = pk2(v1.z, v1.w);
        *(uint4*)(emb16 + h * 8) = o;
    }
}

// ---------------- CSR build (dst-major: seg = dst*8 + r) ----------------
__global__ void count_kernel(const int* __restrict__ ei, const int* __restrict__ et,
                             int* __restrict__ cnt, int E, int N) {
    int e = blockIdx.x * blockDim.x + threadIdx.x;
    if (e < E) atomicAdd(&cnt[ei[E + e] * RNUM + et[e]], 1);
}

__global__ void scan1(const int* __restrict__ in, int* __restrict__ out,
                      int* __restrict__ bsum, int n) {
    __shared__ int s[256];
    const int tid = threadIdx.x;
    const int base = blockIdx.x * SCAN_BS + tid * 8;
    int v[8];
    int sum = 0;
#pragma unroll
    for (int j = 0; j < 8; j++) {
        int x = (base + j < n) ? in[base + j] : 0;
        v[j] = sum;
        sum += x;
    }
    s[tid] = sum;
    __syncthreads();
    for (int off = 1; off < 256; off <<= 1) {
        int tv = (tid >= off) ? s[tid - off] : 0;
        __syncthreads();
        if (tid >= off) s[tid] += tv;
        __syncthreads();
    }
    int excl = (tid > 0) ? s[tid - 1] : 0;
    if (tid == 255) bsum[blockIdx.x] = s[255];
#pragma unroll
    for (int j = 0; j < 8; j++)
        if (base + j < n) out[base + j] = v[j] + excl;
}

__global__ void scan2(int* __restrict__ bsum, int nb) {
    __shared__ int s[512];
    const int tid = threadIdx.x;
    s[tid] = (tid < nb) ? bsum[tid] : 0;
    __syncthreads();
    for (int off = 1; off < 512; off <<= 1) {
        int tv = (tid >= off) ? s[tid - off] : 0;
        __syncthreads();
        if (tid >= off) s[tid] += tv;
        __syncthreads();
    }
    if (tid < nb) bsum[tid] = (tid > 0) ? s[tid - 1] : 0;
}

__global__ void scan3(int* __restrict__ out, int* __restrict__ cur,
                      const int* __restrict__ bsum, int n) {
    const int base = blockIdx.x * SCAN_BS + threadIdx.x * 8;
    const int add = bsum[blockIdx.x];
#pragma unroll
    for (int j = 0; j < 8; j++) {
        int i = base + j;
        if (i < n) {
            int v = out[i] + add;
            out[i] = v;
            cur[i] = v;
        }
    }
}

// fill: col = src node id (layer 2), colE = pre-resolved entity id (layer 1).
// Thread 0 also writes the terminating boundary row_start[8*N] = E.
__global__ void fill_kernel(const int* __restrict__ ei, const int* __restrict__ et,
                            const int* __restrict__ ids,
                            int* __restrict__ cur, int* __restrict__ col,
                            int* __restrict__ colE, int* __restrict__ row_start,
                            int E, int N) {
    int e = blockIdx.x * blockDim.x + threadIdx.x;
    if (e == 0) row_start[RNUM * N] = E;
    if (e < E) {
        int src = ei[e];
        int pos = atomicAdd(&cur[ei[E + e] * RNUM + et[e]], 1);
        col[pos] = src;
        colE[pos] = ids[src];
    }
}

// ---------------- fused layer ----------------
// 256 threads = 4 waves, 64-row tile. LDS = As 16 KB + Ws 32 KB -> 3 blocks/CU.
// dst-major CSR: row's 9 boundaries live in ONE cache line; per-phase s0/s1
// loads are L1-hot. Edge span col[s0..s1) is contiguous per row.
// 64 groups x 4 lanes per block; 3 blocks/CU -> 192 concurrent edge walks/CU.
// Ws(s) staged by async global_load_lds DMA, hidden under the walk.
template <bool HAS_IDX, int ACT>   // ACT: 0 = relu -> bf16 out, 1 = sigmoid -> f32 out
__launch_bounds__(256, 3)
__global__ void rgcn_fused(const int* __restrict__ row_start, const int* __restrict__ col,
                           const int* __restrict__ ids,
                           const unsigned short* __restrict__ x16,
                           const unsigned short* __restrict__ WT,
                           const float* __restrict__ bias,
                           void* __restrict__ CoutV, int N, int E) {
    __shared__ unsigned short As[64 * 128];    // 16 KB
    __shared__ unsigned short Ws[128 * 128];   // 32 KB

    const int tid = threadIdx.x;
    const int block0 = blockIdx.x * 64;
    // MFMA mapping (4 waves: 2 row strips of 32 x 2 col strips of 64)
    const int w = tid >> 6;
    const int lane = tid & 63;
    const int ln15 = lane & 15;
    const int quad = lane >> 4;
    const int rowbase = (w & 1) * 32;
    const int colbase = (w >> 1) * 64;
    // agg mapping: 64 groups of 4 lanes; group g owns row g (64 B per lane)
    const int grp = tid >> 2;
    const int sub4 = tid & 3;
    const int mydst = block0 + grp;
    const bool rowok = (mydst < N);

    float4e acc[2][4];
#pragma unroll
    for (int i = 0; i < 2; i++)
#pragma unroll
        for (int j = 0; j < 4; j++)
#pragma unroll
            for (int q = 0; q < 4; q++) acc[i][j][q] = 0.0f;

#pragma unroll 1
    for (int s = 0; s < RNUM; s++) {
        // ---- stage Ws(s): async DMA; latency hides under the walk below ----
        {
            const unsigned short* Wsrc = WT + s * 16384;
#pragma unroll
            for (int i = 0; i < 8; i++) {
                int c = i * 256 + tid;
                int f = c >> 4;
                int cc = c & 15;
                const void* src = (const void*)(Wsrc + f * 128 + ((cc ^ (f & 15)) << 3));
                int cbase = i * 256 + (tid & ~63);   // wave-uniform base, +lane*16
                gload_lds16(src, (char*)Ws + (size_t)cbase * 16);
            }
        }
        // ---- stage A tile: mean-aggregate; boundaries L1-hot (one line per row) ----
        {
            float4e a[8];
#pragma unroll
            for (int j = 0; j < 8; j++) a[j] = (float4e){0.f, 0.f, 0.f, 0.f};
            int s0 = 0, s1 = 0;
            if (rowok) {
                s0 = row_start[mydst * 8 + s];
                s1 = row_start[mydst * 8 + s + 1];
            }
            const float inv = (s1 > s0) ? 1.0f / (float)(s1 - s0) : 0.0f;
            for (int e = s0; e < s1; e++) {
                int c = col[e];
                const uint4* xp = (const uint4*)(x16 + (size_t)c * HD + sub4 * 32);
                uint4 v0 = xp[0], v1 = xp[1], v2 = xp[2], v3 = xp[3];
                acc2(a[0], v0.x, 0); acc2(a[0], v0.y, 2);
                acc2(a[1], v0.z, 0); acc2(a[1], v0.w, 2);
                acc2(a[2], v1.x, 0); acc2(a[2], v1.y, 2);
                acc2(a[3], v1.z, 0); acc2(a[3], v1.w, 2);
                acc2(a[4], v2.x, 0); acc2(a[4], v2.y, 2);
                acc2(a[5], v2.z, 0); acc2(a[5], v2.w, 2);
                acc2(a[6], v3.x, 0); acc2(a[6], v3.y, 2);
                acc2(a[7], v3.z, 0); acc2(a[7], v3.w, 2);
            }
#pragma unroll
            for (int j = 0; j < 8; j++) a[j] *= inv;
#pragma unroll
            for (int j = 0; j < 4; j++) {
                uint4 o;
                o.x = pk2(a[2 * j][0], a[2 * j][1]);
                o.y = pk2(a[2 * j][2], a[2 * j][3]);
                o.z = pk2(a[2 * j + 1][0], a[2 * j + 1][1]);
                o.w = pk2(a[2 * j + 1][2], a[2 * j + 1][3]);
                int ck = sub4 * 4 + j;
                *(uint4*)&As[grp * 128 + ((ck ^ (grp & 15)) << 3)] = o;
            }
        }
        __syncthreads();

        // ---- MFMA: A and B from LDS ----
#pragma unroll
        for (int k0 = 0; k0 < 4; k0++) {
            short8 af[2], bf[4];
            const int ck = k0 * 4 + quad;
#pragma unroll
            for (int rt = 0; rt < 2; rt++) {
                int m = rowbase + rt * 16 + ln15;
                af[rt] = *(const short8*)&As[m * 128 + ((ck ^ (m & 15)) << 3)];
            }
#pragma unroll
            for (int ct = 0; ct < 4; ct++) {
                int n = colbase + ct * 16 + ln15;
                bf[ct] = *(const short8*)&Ws[n * 128 + ((ck ^ (n & 15)) << 3)];
            }
#pragma unroll
            for (int rt = 0; rt < 2; rt++)
#pragma unroll
                for (int ct = 0; ct < 4; ct++)
                    acc[rt][ct] = __builtin_amdgcn_mfma_f32_16x16x32_bf16(
                        af[rt], bf[ct], acc[rt][ct], 0, 0, 0);
        }
        __syncthreads();
    }

    // ---- root/self phase (s == 8) ----
    {
        const unsigned short* Wsrc = WT + RNUM * 16384;
#pragma unroll
        for (int i = 0; i < 8; i++) {
            int c = i * 256 + tid;
            int f = c >> 4;
            int cc = c & 15;
            const void* src = (const void*)(Wsrc + f * 128 + ((cc ^ (f & 15)) << 3));
            int cbase = i * 256 + (tid & ~63);
            gload_lds16(src, (char*)Ws + (size_t)cbase * 16);
        }
        uint4 o0 = {0u, 0u, 0u, 0u}, o1 = o0, o2 = o0, o3 = o0;
        if (rowok) {
            int srcn = HAS_IDX ? ids[mydst] : mydst;
            const uint4* xp = (const uint4*)(x16 + (size_t)srcn * HD + sub4 * 32);
            o0 = xp[0]; o1 = xp[1]; o2 = xp[2]; o3 = xp[3];
        }
        const int ck0 = sub4 * 4;
        *(uint4*)&As[grp * 128 + (((ck0 + 0) ^ (grp & 15)) << 3)] = o0;
        *(uint4*)&As[grp * 128 + (((ck0 + 1) ^ (grp & 15)) << 3)] = o1;
        *(uint4*)&As[grp * 128 + (((ck0 + 2) ^ (grp & 15)) << 3)] = o2;
        *(uint4*)&As[grp * 128 + (((ck0 + 3) ^ (grp & 15)) << 3)] = o3;
        __syncthreads();
#pragma unroll
        for (int k0 = 0; k0 < 4; k0++) {
            short8 af[2], bf[4];
            const int ck = k0 * 4 + quad;
#pragma unroll
            for (int rt = 0; rt < 2; rt++) {
                int m = rowbase + rt * 16 + ln15;
                af[rt] = *(const short8*)&As[m * 128 + ((ck ^ (m & 15)) << 3)];
            }
#pragma unroll
            for (int ct = 0; ct < 4; ct++) {
                int n = colbase + ct * 16 + ln15;
                bf[ct] = *(const short8*)&Ws[n * 128 + ((ck ^ (n & 15)) << 3)];
            }
#pragma unroll
            for (int rt = 0; rt < 2; rt++)
#pragma unroll
                for (int ct = 0; ct < 4; ct++)
                    acc[rt][ct] = __builtin_amdgcn_mfma_f32_16x16x32_bf16(
                        af[rt], bf[ct], acc[rt][ct], 0, 0, 0);
        }
        __syncthreads();
    }

    // ---- epilogue ----
#pragma unroll
    for (int ct = 0; ct < 4; ct++) {
        int ncol = colbase + ct * 16 + ln15;
        float bv = bias[ncol];
#pragma unroll
        for (int rt = 0; rt < 2; rt++) {
#pragma unroll
            for (int rg = 0; rg < 4; rg++) {
                int rowg = block0 + rowbase + rt * 16 + quad * 4 + rg;
                if (rowg < N) {
                    float v = acc[rt][ct][rg] + bv;
                    if (ACT == 0) {
                        v = fmaxf(v, 0.0f);
                        ((unsigned short*)CoutV)[(size_t)rowg * HD + ncol] = f2bf(v);
                    } else {
                        v = 1.0f / (1.0f + expf(-v));
                        ((float*)CoutV)[(size_t)rowg * HD + ncol] = v;
                    }
                }
            }
        }
    }
}

extern "C" void kernel_launch(void* const* d_in, const int* in_sizes, int n_in,
                              void* d_out, int out_size, void* d_ws, size_t ws_size,
                              hipStream_t stream) {
    const int*   x_ids = (const int*)d_in[0];
    const int*   ei    = (const int*)d_in[1];
    const int*   et    = (const int*)d_in[2];
    const float* emb   = (const float*)d_in[3];
    const float* W1    = (const float*)d_in[4];
    const float* root1 = (const float*)d_in[5];
    const float* b1    = (const float*)d_in[6];
    const float* W2    = (const float*)d_in[7];
    const float* root2 = (const float*)d_in[8];
    const float* b2    = (const float*)d_in[9];

    const int N = in_sizes[0];
    const int E = in_sizes[1] / 2;
    const int NS = RNUM * N;
    const long long embElems = (long long)in_sizes[3];   // NUM_ENTITIES * HD
    float* out = (float*)d_out;

    // ---- arenas (row_start has NS+1 entries, padded to 16 B) ----
    char* ws = (char*)d_ws;
    size_t off = 0;
    int* row_start = (int*)(ws + off); off += (size_t)(NS + 4) * 4;             // 3.2 MB
    int* col       = (int*)(ws + off); off += (size_t)E * 4;                    // 2.0 MB
    int* colE      = (int*)(ws + off); off += (size_t)E * 4;                    // 2.0 MB
    int* bsum      = (int*)(ws + off); off += 4096;
    unsigned short* WT    = (unsigned short*)(ws + off); off += (size_t)18 * 16384 * 2;
    unsigned short* emb16 = (unsigned short*)(ws + off); off += (size_t)embElems * 2;  // 25.6 MB
    unsigned short* z16   = (unsigned short*)(ws + off); off += (size_t)N * HD * 2;    // 25.6 MB
    int* cur = (int*)z16;   // alias: cur dead before z16 is first written

    const int scanBlocks = (NS + SCAN_BS - 1) / SCAN_BS;
    const int layerGrid = (N + 63) / 64;

    // ---- CSR build (dst-major) ----
    zero_i<<<(NS + 255) / 256, 256, 0, stream>>>(cur, NS);
    count_kernel<<<(E + 255) / 256, 256, 0, stream>>>(ei, et, cur, E, N);
    scan1<<<scanBlocks, 256, 0, stream>>>(cur, row_start, bsum, NS);
    scan2<<<1, 512, 0, stream>>>(bsum, scanBlocks);
    scan3<<<scanBlocks, 256, 0, stream>>>(row_start, cur, bsum, NS);
    fill_kernel<<<(E + 255) / 256, 256, 0, stream>>>(ei, et, x_ids, cur, col, colE,
                                                     row_start, E, N);

    // ---- weights -> bf16 transposed + emb -> bf16 (one launch) ----
    {
        long long n8 = embElems / 8;
        long long total = 18 * 16384 + n8;
        prep_kernel<<<(unsigned int)((total + 255) / 256), 256, 0, stream>>>(
            W1, root1, W2, root2, WT, emb, emb16, n8);
    }

    // ---- layer 1: z16 = bf16(relu(agg(emb16) + emb16[ids]@root1 + b1)) ----
    rgcn_fused<true, 0><<<layerGrid, 256, 0, stream>>>(
        row_start, colE, x_ids, emb16, WT, b1, (void*)z16, N, E);
    // ---- layer 2: out = sigmoid(agg(z16) + z16@root2 + b2) ----
    rgcn_fused<false, 1><<<layerGrid, 256, 0, stream>>>(
        row_start, col, nullptr, z16, WT + 9 * 16384, b2, (void*)out, N, E);
}